// Round 2
// baseline (295.903 us; speedup 1.0000x reference)
//
#include <hip/hip_runtime.h>
#include <hip/hip_bf16.h>

// z [65536,256] f32, embeddings [1024,256] f32
// out = quantized_st [65536*256] f32 ++ loss scalar
#define NROWS 65536
#define DIM   256
#define KCB   1024
#define ND    (NROWS * DIM)

typedef float f32x4  __attribute__((ext_vector_type(4)));
typedef short bf16x8 __attribute__((ext_vector_type(8)));

// workspace layout (bytes)
#define WS_LOSS    0                       // float
#define WS_COUNTER 4                       // int (gather block counter)
#define WS_ENORM   256                     // float[1024]
#define WS_PACK    8192                    // u64[2][65536] = 1 MiB (score|idx per K-half)
#define WS_E       (8192 + 2 * 65536 * 8)  // bf16x8[16*2048] = 512 KiB, staging-permuted
// total: ~1.52 MiB

typedef __attribute__((address_space(1))) const void gas_void;
typedef __attribute__((address_space(3))) void       las_void;

// fp32 -> bf16 bits, round-to-nearest-even
static __device__ __forceinline__ short f2bf(float f) {
    union { float f; unsigned u; } v; v.f = f;
    unsigned u = v.u;
    unsigned r = (u + 0x7fffu + ((u >> 16) & 1u)) >> 16;
    return (short)(unsigned short)r;
}

// ---------------------------------------------------------------------------
// Prep: e_norm fp32 + E -> bf16 in MFMA staging-permuted order; zero accums.
// Permuted id in a 64-row chunk: id = (t*8+s)*64 + q*16 + l,
// emb row = t*16+l, d-chunk c = s*4+q (8 bf16 each).
// ---------------------------------------------------------------------------
__global__ __launch_bounds__(256) void prep_e(const float* __restrict__ E,
                                              float* __restrict__ enorm,
                                              bf16x8* __restrict__ wsE,
                                              float* __restrict__ loss_acc,
                                              int* __restrict__ counter) {
    __shared__ float part[64][4];
    const int tid = threadIdx.x;
    const int blk = blockIdx.x;  // 0..15

    if (blk == 0 && tid == 0) { *loss_acc = 0.f; *counter = 0; }

    {   // e_norm fp32
        const float4* E4 = (const float4*)E;
        int row = tid >> 2, qq = tid & 3;
        int base = (blk * 64 + row) * 64 + qq * 16;
        float s = 0.f;
#pragma unroll
        for (int u = 0; u < 16; ++u) {
            float4 f = E4[base + u];
            s += f.x * f.x + f.y * f.y + f.z * f.z + f.w * f.w;
        }
        part[row][qq] = s;
    }
    __syncthreads();
    if (tid < 64)
        enorm[blk * 64 + tid] = part[tid][0] + part[tid][1] + part[tid][2] + part[tid][3];

    const float4* E4 = (const float4*)E;
#pragma unroll
    for (int j = 0; j < 8; ++j) {
        int id = tid + 256 * j;                 // 0..2047
        int l = id & 15, q = (id >> 4) & 3, s = (id >> 6) & 7, t = (id >> 9) & 3;
        int row = t * 16 + l;
        int c   = s * 4 + q;
        int fi  = (blk * 64 + row) * 64 + c * 2;
        float4 f0 = E4[fi], f1 = E4[fi + 1];
        bf16x8 o;
        o[0] = f2bf(f0.x); o[1] = f2bf(f0.y); o[2] = f2bf(f0.z); o[3] = f2bf(f0.w);
        o[4] = f2bf(f1.x); o[5] = f2bf(f1.y); o[6] = f2bf(f1.z); o[7] = f2bf(f1.w);
        wsE[blk * 2048 + id] = o;
    }
}

// ---------------------------------------------------------------------------
// Main: score-GEMM (bf16 MFMA) + per-K-half argmin. 2-way K-split:
// block pair (2i,2i+1) = same 128 z-rows, codebook halves. grid=1024 ->
// 4 blocks/CU (16 waves/CU). Staging via global_load_lds width=16.
// Writes packed (score_bits<<32 | idx) per row per half; accumulates
// sum(||z||^2) into loss_acc (half 0 only).
// ---------------------------------------------------------------------------
__global__ __launch_bounds__(256, 4) void vq_main(const float* __restrict__ Z,
                                                  const float* __restrict__ enorm,
                                                  const bf16x8* __restrict__ wsE,
                                                  unsigned long long* __restrict__ pack,
                                                  float* __restrict__ loss_acc) {
    __shared__ bf16x8 Es[2048];     // 32 KiB chunk, staging order
    __shared__ float  enorm_s[64];

    const int tid  = threadIdx.x;
    const int w    = tid >> 6;
    const int lane = tid & 63;
    const int q    = lane >> 4;
    const int l    = lane & 15;
    const int bid    = blockIdx.x;
    const int ksplit = bid & 1;       // which codebook half
    const int rowseg = bid >> 1;      // 0..511, 128 rows each

    // ---- A fragments (z rows) into registers; fp32 ||z||^2 ----
    bf16x8 zf[2][8];
    float zsum = 0.f;
    const float4* Z4 = (const float4*)Z;
#pragma unroll
    for (int rt = 0; rt < 2; ++rt) {
        int row = rowseg * 128 + w * 32 + rt * 16 + l;
        float zn = 0.f;
#pragma unroll
        for (int s = 0; s < 8; ++s) {
            int fi = row * 64 + s * 8 + q * 2;
            float4 f0 = Z4[fi], f1 = Z4[fi + 1];
            zn += f0.x * f0.x + f0.y * f0.y + f0.z * f0.z + f0.w * f0.w;
            zn += f1.x * f1.x + f1.y * f1.y + f1.z * f1.z + f1.w * f1.w;
            bf16x8 o;
            o[0] = f2bf(f0.x); o[1] = f2bf(f0.y); o[2] = f2bf(f0.z); o[3] = f2bf(f0.w);
            o[4] = f2bf(f1.x); o[5] = f2bf(f1.y); o[6] = f2bf(f1.z); o[7] = f2bf(f1.w);
            zf[rt][s] = o;
        }
        zn += __shfl_xor(zn, 16, 64);   // sum the 4 q-quarters -> full row norm
        zn += __shfl_xor(zn, 32, 64);
        zsum += zn;
    }
    // wave total of 32 distinct row-norms: q-groups are duplicates, so
    // butterfly only over l (xor 1..8); result replicated, lane 0 commits.
#pragma unroll
    for (int m = 1; m <= 8; m <<= 1) zsum += __shfl_xor(zsum, m, 64);
    if (ksplit == 0 && lane == 0) atomicAdd(loss_acc, zsum);

    float minv[2][4];
    int   mini[2][4];
#pragma unroll
    for (int rt = 0; rt < 2; ++rt)
#pragma unroll
        for (int r = 0; r < 4; ++r) { minv[rt][r] = 3.4e38f; mini[rt][r] = 0; }

    // ---- K sweep: 8 chunks of 64 embeddings ----
    for (int kc = 0; kc < 8; ++kc) {
        const int kcg = ksplit * 8 + kc;
        __syncthreads();   // previous chunk's LDS reads done
        // async stage: wave-uniform LDS base + lane*16, contiguous
        {
            const bf16x8* src = wsE + kcg * 2048;
#pragma unroll
            for (int j = 0; j < 8; ++j) {
                int id = j * 256 + w * 64;
                __builtin_amdgcn_global_load_lds((gas_void*)(src + id + lane),
                                                 (las_void*)(&Es[id]), 16, 0, 0);
            }
        }
        if (tid < 64) enorm_s[tid] = enorm[kcg * 64 + tid];
        __syncthreads();   // drains vmcnt -> staging complete

        f32x4 acc[2][4];
#pragma unroll
        for (int rt = 0; rt < 2; ++rt)
#pragma unroll
            for (int t = 0; t < 4; ++t) acc[rt][t] = (f32x4){0.f, 0.f, 0.f, 0.f};

#pragma unroll
        for (int s = 0; s < 8; ++s) {
            bf16x8 b0 = Es[(0 * 8 + s) * 64 + lane];
            bf16x8 b1 = Es[(1 * 8 + s) * 64 + lane];
            bf16x8 b2 = Es[(2 * 8 + s) * 64 + lane];
            bf16x8 b3 = Es[(3 * 8 + s) * 64 + lane];
            acc[0][0] = __builtin_amdgcn_mfma_f32_16x16x32_bf16(zf[0][s], b0, acc[0][0], 0, 0, 0);
            acc[0][1] = __builtin_amdgcn_mfma_f32_16x16x32_bf16(zf[0][s], b1, acc[0][1], 0, 0, 0);
            acc[0][2] = __builtin_amdgcn_mfma_f32_16x16x32_bf16(zf[0][s], b2, acc[0][2], 0, 0, 0);
            acc[0][3] = __builtin_amdgcn_mfma_f32_16x16x32_bf16(zf[0][s], b3, acc[0][3], 0, 0, 0);
            acc[1][0] = __builtin_amdgcn_mfma_f32_16x16x32_bf16(zf[1][s], b0, acc[1][0], 0, 0, 0);
            acc[1][1] = __builtin_amdgcn_mfma_f32_16x16x32_bf16(zf[1][s], b1, acc[1][1], 0, 0, 0);
            acc[1][2] = __builtin_amdgcn_mfma_f32_16x16x32_bf16(zf[1][s], b2, acc[1][2], 0, 0, 0);
            acc[1][3] = __builtin_amdgcn_mfma_f32_16x16x32_bf16(zf[1][s], b3, acc[1][3], 0, 0, 0);
        }

        // C/D layout: col = lane&15 (embedding), row = q*4+reg (z row)
#pragma unroll
        for (int t = 0; t < 4; ++t) {
            float en   = enorm_s[t * 16 + l];
            int   kidx = kcg * 64 + t * 16 + l;
#pragma unroll
            for (int rt = 0; rt < 2; ++rt)
#pragma unroll
                for (int r = 0; r < 4; ++r) {
                    float sc = en - 2.f * acc[rt][t][r];
                    bool better = sc < minv[rt][r];   // strict '<': earliest k wins ties
                    mini[rt][r] = better ? kidx : mini[rt][r];
                    minv[rt][r] = better ? sc : minv[rt][r];
                }
        }
    }

    // ---- cross-lane argmin over the 16 column-lanes; commit packed result ----
#pragma unroll
    for (int rt = 0; rt < 2; ++rt)
#pragma unroll
        for (int r = 0; r < 4; ++r) {
            float v  = minv[rt][r];
            int   id = mini[rt][r];
#pragma unroll
            for (int m = 1; m <= 8; m <<= 1) {
                float ov = __shfl_xor(v, m, 64);
                int   oi = __shfl_xor(id, m, 64);
                if (ov < v || (ov == v && oi < id)) { v = ov; id = oi; }
            }
            if (l == 0) {
                int grow = rowseg * 128 + w * 32 + rt * 16 + q * 4 + r;
                pack[ksplit * 65536 + grow] =
                    ((unsigned long long)__float_as_uint(v) << 32) | (unsigned)id;
            }
        }
}

// ---------------------------------------------------------------------------
// Gather: merge the two K-half argmins, stream E[closest] rows to out,
// accumulate sum(min_score); last block finalizes the loss scalar.
// ---------------------------------------------------------------------------
__global__ __launch_bounds__(256) void vq_gather(const float* __restrict__ E,
                                                 const unsigned long long* __restrict__ pack,
                                                 float* __restrict__ out,
                                                 float* __restrict__ loss_acc,
                                                 int* __restrict__ counter) {
    __shared__ int cls[128];
    const int tid = threadIdx.x;
    const int bid = blockIdx.x;   // 512 blocks x 128 rows

    float lossp = 0.f;
    if (tid < 128) {
        int row = bid * 128 + tid;
        unsigned long long p0 = pack[row], p1 = pack[65536 + row];
        float f0 = __uint_as_float((unsigned)(p0 >> 32));
        float f1 = __uint_as_float((unsigned)(p1 >> 32));
        bool take1 = f1 < f0;                 // tie -> half 0 (smaller indices)
        cls[tid] = (int)(unsigned)(take1 ? p1 : p0);
        lossp = take1 ? f1 : f0;              // min score; ||z||^2 added in vq_main
    }
#pragma unroll
    for (int m = 1; m <= 32; m <<= 1) lossp += __shfl_xor(lossp, m, 64);
    if ((tid & 63) == 0) atomicAdd(loss_acc, lossp);
    __syncthreads();

    const float4* E4 = (const float4*)E;
    float4* O4 = (float4*)out;
#pragma unroll
    for (int u = 0; u < 32; ++u) {
        int idx = u * 256 + tid;
        int row = idx >> 6;
        int c4  = idx & 63;
        int k   = cls[row];
        O4[(bid * 128 + row) * 64 + c4] = E4[k * 64 + c4];
    }

    __threadfence();
    if (tid == 0) {
        if (atomicAdd(counter, 1) == 511) {
            float tot = atomicAdd(loss_acc, 0.0f);   // coherent device-scope read
            out[ND] = 1.25f * tot / (float)ND;       // codebook + 0.25*commitment
        }
    }
}

extern "C" void kernel_launch(void* const* d_in, const int* in_sizes, int n_in,
                              void* d_out, int out_size, void* d_ws, size_t ws_size,
                              hipStream_t stream) {
    const float* z = (const float*)d_in[0];
    const float* e = (const float*)d_in[1];
    float* out = (float*)d_out;
    char*  ws  = (char*)d_ws;
    float*               loss_acc = (float*)(ws + WS_LOSS);
    int*                 counter  = (int*)(ws + WS_COUNTER);
    float*               enorm    = (float*)(ws + WS_ENORM);
    unsigned long long*  pack     = (unsigned long long*)(ws + WS_PACK);
    bf16x8*              wsE      = (bf16x8*)(ws + WS_E);

    prep_e<<<16, 256, 0, stream>>>(e, enorm, wsE, loss_acc, counter);
    vq_main<<<1024, 256, 0, stream>>>(z, enorm, wsE, pack, loss_acc);
    vq_gather<<<512, 256, 0, stream>>>(e, pack, out, loss_acc, counter);
}

// Round 3
// 227.551 us; speedup vs baseline: 1.3004x; 1.3004x over previous
//
#include <hip/hip_runtime.h>
#include <hip/hip_bf16.h>

// z [65536,256] f32, embeddings [1024,256] f32
// out = quantized_st [65536*256] f32 ++ loss scalar
#define NROWS 65536
#define DIM   256
#define KCB   1024
#define ND    (NROWS * DIM)

typedef float f32x4  __attribute__((ext_vector_type(4)));
typedef short bf16x8 __attribute__((ext_vector_type(8)));

// workspace layout (bytes)
#define WS_LOSS    0      // float
#define WS_COUNTER 4      // int (finalize block counter)
#define WS_ENORM   256    // float[1024]
#define WS_E       8192   // bf16x8[32 chunks][1024 ids] = 512 KiB, staging-permuted
// total: ~520 KiB

typedef __attribute__((address_space(1))) const void gas_void;
typedef __attribute__((address_space(3))) void       las_void;

// fp32 -> bf16 bits, round-to-nearest-even
static __device__ __forceinline__ short f2bf(float f) {
    union { float f; unsigned u; } v; v.f = f;
    unsigned u = v.u;
    unsigned r = (u + 0x7fffu + ((u >> 16) & 1u)) >> 16;
    return (short)(unsigned short)r;
}

// ---------------------------------------------------------------------------
// Prep: e_norm fp32 + E -> bf16 in MFMA staging-permuted order (32-emb chunks).
// Within a 32-emb chunk: id = (t*8+s)*64 + q*16 + l, t in {0,1};
// emb row = chunk*32 + t*16 + l; d-chunk cdim = s*4+q (8 bf16 each).
// ---------------------------------------------------------------------------
__global__ __launch_bounds__(256) void prep_e(const float* __restrict__ E,
                                              float* __restrict__ enorm,
                                              bf16x8* __restrict__ wsE,
                                              float* __restrict__ loss_acc,
                                              int* __restrict__ counter) {
    __shared__ float part[64][4];
    const int tid = threadIdx.x;
    const int blk = blockIdx.x;  // 0..15

    if (blk == 0 && tid == 0) { *loss_acc = 0.f; *counter = 0; }

    {   // e_norm fp32
        const float4* E4 = (const float4*)E;
        int row = tid >> 2, qq = tid & 3;
        int base = (blk * 64 + row) * 64 + qq * 16;
        float s = 0.f;
#pragma unroll
        for (int u = 0; u < 16; ++u) {
            float4 f = E4[base + u];
            s += f.x * f.x + f.y * f.y + f.z * f.z + f.w * f.w;
        }
        part[row][qq] = s;
    }
    __syncthreads();
    if (tid < 64)
        enorm[blk * 64 + tid] = part[tid][0] + part[tid][1] + part[tid][2] + part[tid][3];

    const float4* E4 = (const float4*)E;
#pragma unroll
    for (int j = 0; j < 8; ++j) {
        int g  = blk * 2048 + j * 256 + tid;    // 0..32767, contiguous writes
        int ch = g >> 10;                       // 32-emb chunk
        int id = g & 1023;
        int l = id & 15, q = (id >> 4) & 3, s = (id >> 6) & 7, t = (id >> 9) & 1;
        int erow = ch * 32 + t * 16 + l;
        int cdim = s * 4 + q;
        int fi   = erow * 64 + cdim * 2;
        float4 f0 = E4[fi], f1 = E4[fi + 1];
        bf16x8 o;
        o[0] = f2bf(f0.x); o[1] = f2bf(f0.y); o[2] = f2bf(f0.z); o[3] = f2bf(f0.w);
        o[4] = f2bf(f1.x); o[5] = f2bf(f1.y); o[6] = f2bf(f1.z); o[7] = f2bf(f1.w);
        wsE[g] = o;
    }
}

// ---------------------------------------------------------------------------
// Main: fused score-GEMM (bf16 MFMA) + argmin + gather + loss.
// 1024 blocks x 128 thr (2 waves x 32 rows = 64 rows/block) -> 4 blocks/CU:
// 4 independent barrier-groups per CU so staging drains overlap compute.
// K sweep: 32 chunks of 32 embeddings (16 KiB LDS), global_load_lds width=16.
// z read once (no K-split). Last block finalizes the loss scalar.
// ---------------------------------------------------------------------------
__global__ __launch_bounds__(128, 2) void vq_main(const float* __restrict__ Z,
                                                  const float* __restrict__ E,
                                                  const float* __restrict__ enorm,
                                                  const bf16x8* __restrict__ wsE,
                                                  float* __restrict__ out,
                                                  float* __restrict__ loss_acc,
                                                  int* __restrict__ counter) {
    __shared__ bf16x8 Es[1024];     // 16 KiB chunk, staging order
    __shared__ float  enorm_s[32];
    __shared__ float  znorm_s[64];
    __shared__ int    closest_s[64];
    __shared__ float  blk_loss;

    const int tid  = threadIdx.x;
    const int w    = tid >> 6;      // 0..1
    const int lane = tid & 63;
    const int q    = lane >> 4;
    const int l    = lane & 15;
    const int blk  = blockIdx.x;    // 0..1023, 64 rows each

    if (tid == 0) blk_loss = 0.f;

    // ---- A fragments (z rows) into registers; fp32 ||z||^2 ----
    bf16x8 zf[2][8];
    const float4* Z4 = (const float4*)Z;
#pragma unroll
    for (int rt = 0; rt < 2; ++rt) {
        int row = blk * 64 + w * 32 + rt * 16 + l;
        float zn = 0.f;
#pragma unroll
        for (int s = 0; s < 8; ++s) {
            int fi = row * 64 + s * 8 + q * 2;
            float4 f0 = Z4[fi], f1 = Z4[fi + 1];
            zn += f0.x * f0.x + f0.y * f0.y + f0.z * f0.z + f0.w * f0.w;
            zn += f1.x * f1.x + f1.y * f1.y + f1.z * f1.z + f1.w * f1.w;
            bf16x8 o;
            o[0] = f2bf(f0.x); o[1] = f2bf(f0.y); o[2] = f2bf(f0.z); o[3] = f2bf(f0.w);
            o[4] = f2bf(f1.x); o[5] = f2bf(f1.y); o[6] = f2bf(f1.z); o[7] = f2bf(f1.w);
            zf[rt][s] = o;
        }
        zn += __shfl_xor(zn, 16, 64);   // sum 4 q-quarters -> full row norm
        zn += __shfl_xor(zn, 32, 64);
        if (q == 0) znorm_s[w * 32 + rt * 16 + l] = zn;
    }

    float minv[2][4];
    int   mini[2][4];
#pragma unroll
    for (int rt = 0; rt < 2; ++rt)
#pragma unroll
        for (int r = 0; r < 4; ++r) { minv[rt][r] = 3.4e38f; mini[rt][r] = 0; }

    // ---- K sweep: 32 chunks of 32 embeddings ----
    for (int kc = 0; kc < 32; ++kc) {
        __syncthreads();   // previous chunk's LDS reads done (also covers init)
        {   // async stage: wave-uniform LDS base + lane*16, contiguous
            const bf16x8* src = wsE + kc * 1024;
#pragma unroll
            for (int j = 0; j < 8; ++j) {
                int id = j * 128 + w * 64;
                __builtin_amdgcn_global_load_lds((gas_void*)(src + id + lane),
                                                 (las_void*)(&Es[id]), 16, 0, 0);
            }
        }
        if (tid < 32) enorm_s[tid] = enorm[kc * 32 + tid];
        __syncthreads();   // drains vmcnt -> staging complete

        f32x4 acc[2][2];
#pragma unroll
        for (int rt = 0; rt < 2; ++rt)
#pragma unroll
            for (int t = 0; t < 2; ++t) acc[rt][t] = (f32x4){0.f, 0.f, 0.f, 0.f};

#pragma unroll
        for (int s = 0; s < 8; ++s) {
            bf16x8 b0 = Es[(0 * 8 + s) * 64 + lane];
            bf16x8 b1 = Es[(1 * 8 + s) * 64 + lane];
            acc[0][0] = __builtin_amdgcn_mfma_f32_16x16x32_bf16(zf[0][s], b0, acc[0][0], 0, 0, 0);
            acc[0][1] = __builtin_amdgcn_mfma_f32_16x16x32_bf16(zf[0][s], b1, acc[0][1], 0, 0, 0);
            acc[1][0] = __builtin_amdgcn_mfma_f32_16x16x32_bf16(zf[1][s], b0, acc[1][0], 0, 0, 0);
            acc[1][1] = __builtin_amdgcn_mfma_f32_16x16x32_bf16(zf[1][s], b1, acc[1][1], 0, 0, 0);
        }

        // C/D layout: col = lane&15 (embedding), row = q*4+reg (z row)
#pragma unroll
        for (int t = 0; t < 2; ++t) {
            float en   = enorm_s[t * 16 + l];
            int   kidx = kc * 32 + t * 16 + l;
#pragma unroll
            for (int rt = 0; rt < 2; ++rt)
#pragma unroll
                for (int r = 0; r < 4; ++r) {
                    float sc = en - 2.f * acc[rt][t][r];
                    bool better = sc < minv[rt][r];   // strict '<': earliest k wins ties
                    mini[rt][r] = better ? kidx : mini[rt][r];
                    minv[rt][r] = better ? sc : minv[rt][r];
                }
        }
    }

    // ---- cross-lane argmin over the 16 column-lanes; commit to LDS ----
    float lossp = 0.f;
#pragma unroll
    for (int rt = 0; rt < 2; ++rt)
#pragma unroll
        for (int r = 0; r < 4; ++r) {
            float v  = minv[rt][r];
            int   id = mini[rt][r];
#pragma unroll
            for (int m = 1; m <= 8; m <<= 1) {
                float ov = __shfl_xor(v, m, 64);
                int   oi = __shfl_xor(id, m, 64);
                if (ov < v || (ov == v && oi < id)) { v = ov; id = oi; }
            }
            if (l == 0) {
                int rloc = w * 32 + rt * 16 + q * 4 + r;
                closest_s[rloc] = id;
                lossp += v + znorm_s[rloc];   // ||z-e*||^2
            }
        }
    if (l == 0) atomicAdd(&blk_loss, lossp);
    __syncthreads();
    if (tid == 0) atomicAdd(loss_acc, blk_loss);

    // ---- gather epilogue: out rows = E[closest] fp32 (exact values) ----
    const float4* E4 = (const float4*)E;
    float4* O4 = (float4*)out;
#pragma unroll
    for (int u = 0; u < 32; ++u) {
        int idx = u * 128 + tid;          // 0..4095
        int row = idx >> 6;               // wave-uniform per iteration
        int c4  = idx & 63;
        int k   = closest_s[row];
        O4[(blk * 64 + row) * 64 + c4] = E4[k * 64 + c4];
    }

    // ---- last block finalizes the loss scalar ----
    __threadfence();
    if (tid == 0) {
        if (atomicAdd(counter, 1) == 1023) {
            float tot = atomicAdd(loss_acc, 0.0f);   // coherent device-scope read
            out[ND] = 1.25f * tot / (float)ND;       // codebook + 0.25*commitment
        }
    }
}

extern "C" void kernel_launch(void* const* d_in, const int* in_sizes, int n_in,
                              void* d_out, int out_size, void* d_ws, size_t ws_size,
                              hipStream_t stream) {
    const float* z = (const float*)d_in[0];
    const float* e = (const float*)d_in[1];
    float* out = (float*)d_out;
    char*  ws  = (char*)d_ws;
    float*  loss_acc = (float*)(ws + WS_LOSS);
    int*    counter  = (int*)(ws + WS_COUNTER);
    float*  enorm    = (float*)(ws + WS_ENORM);
    bf16x8* wsE      = (bf16x8*)(ws + WS_E);

    prep_e<<<16, 256, 0, stream>>>(e, enorm, wsE, loss_acc, counter);
    vq_main<<<1024, 128, 0, stream>>>(z, e, enorm, wsE, out, loss_acc, counter);
}